// Round 9
// baseline (195.395 us; speedup 1.0000x reference)
//
#include <hip/hip_runtime.h>
#include <hip/hip_bf16.h>
#include <stdint.h>

#define BB     8
#define CC     320
#define NN     4096
#define SKV    77
#define HEADS  8
#define INNER  512
#define SCALE  0.125f

typedef float f32x4  __attribute__((ext_vector_type(4)));
typedef short bf16x8 __attribute__((ext_vector_type(8)));
typedef short s16x4  __attribute__((ext_vector_type(4)));

static __device__ __forceinline__ short f2bf(float f) {
  unsigned u = __float_as_uint(f);
  return (short)((u + 0x7fffu + ((u >> 16) & 1u)) >> 16);
}

// async global->LDS 16B copy; LDS dest is wave-uniform base + lane*16.
static __device__ __forceinline__ void gll16(void* lds, const void* g) {
  auto gp = reinterpret_cast<const uint32_t __attribute__((address_space(1)))*>(
      reinterpret_cast<uintptr_t>(g));
  auto lp = reinterpret_cast<uint32_t __attribute__((address_space(3)))*>(
      reinterpret_cast<uintptr_t>(lds));
  __builtin_amdgcn_global_load_lds(gp, lp, 16, 0, 0);
}

// ---------------------------------------------------------------------------
// prep (+xpose merged): kv->bf16 | Wk,Wv,Wq(x SCALE),Wo tiled transposes |
// zero K_ws/V_ws | query -> X_bf 64x64 tiles.
// blocks: [0,616) kv | [616,872) Wk/Wv | [872,912) Wq | [912,952) Wo |
// [952,1392) zero | [1392,3952) xpose
// ---------------------------------------------------------------------------
__global__ __launch_bounds__(256) void prep_kernel(
    const float* __restrict__ kv, const float* __restrict__ Wk,
    const float* __restrict__ Wv, const float* __restrict__ Wq,
    const float* __restrict__ Wo, const float* __restrict__ query,
    short* __restrict__ kv_bf, short* __restrict__ Wk_t,
    short* __restrict__ Wv_t, short* __restrict__ Wq_t,
    short* __restrict__ Wo_t, short* __restrict__ X_bf,
    unsigned* __restrict__ zero_base) {
  __shared__ float T[64 * 65];
  const int blk = blockIdx.x, t = threadIdx.x;
  if (blk < 616) {
    const int base = blk * 1024;
    #pragma unroll
    for (int i = 0; i < 4; ++i) kv_bf[base + i*256 + t] = f2bf(kv[base + i*256 + t]);
    return;
  }
  if (blk >= 1392) {              // xpose: query [b][c][n] -> X_bf [b*N+n][320]
    const int blk2 = blk - 1392;
    const int b = blk2 / 320, r = blk2 % 320;
    const int nt = r / 5, ct = r % 5;
    const int tl = t & 63, rb = t >> 6;
    #pragma unroll
    for (int i = 0; i < 16; ++i) {
      const int c = rb + i*4;
      T[c*65 + tl] = query[((size_t)(b*CC + ct*64 + c))*NN + nt*64 + tl];
    }
    __syncthreads();
    #pragma unroll
    for (int i = 0; i < 16; ++i) {
      const int n = rb + i*4;
      X_bf[((size_t)(b*NN + nt*64 + n))*CC + ct*64 + tl] = f2bf(T[tl*65 + n]);
    }
    return;
  }
  if (blk >= 952) {
    const int base = (blk - 952) * 1024;
    #pragma unroll
    for (int i = 0; i < 4; ++i) zero_base[base + i*256 + t] = 0u;
    return;
  }
  const float* src; short* dst; int RS, CS, kt, ct; float scl = 1.0f;
  if (blk < 872) {               // Wk/Wv: [1024][512] -> [512][1024]
    const int tile = blk - 616;
    const bool isK = tile < 128;
    const int tt = isK ? tile : tile - 128;
    src = isK ? Wk : Wv; dst = isK ? Wk_t : Wv_t;
    RS = 1024; CS = 512; kt = tt >> 3; ct = tt & 7;
  } else if (blk < 912) {        // Wq: [320][512] -> [512][320], x SCALE
    const int tt = blk - 872;
    src = Wq; dst = Wq_t; RS = 320; CS = 512; kt = tt >> 3; ct = tt & 7;
    scl = SCALE;
  } else {                       // Wo: [512][320] -> [320][512]
    const int tt = blk - 912;
    src = Wo; dst = Wo_t; RS = 512; CS = 320; kt = tt / 5; ct = tt % 5;
  }
  const int cl = t & 63, rb = t >> 6;
  #pragma unroll
  for (int i = 0; i < 16; ++i)
    T[(rb + i*4)*65 + cl] = src[(size_t)(kt*64 + rb + i*4)*CS + ct*64 + cl];
  __syncthreads();
  #pragma unroll
  for (int i = 0; i < 16; ++i) {
    const int nl = rb + i*4;
    dst[(size_t)(ct*64 + nl)*RS + kt*64 + cl] = f2bf(T[cl*65 + nl] * scl);
  }
}

// ---------------------------------------------------------------------------
// kvproj: [616,1024]bf16 @ Wk_t/Wv_t -> K_ws [b][h][80][64], V_ws [b][h][64][96]
// ---------------------------------------------------------------------------
__global__ __launch_bounds__(256) void kvproj_kernel(
    const short* __restrict__ kv_bf, const short* __restrict__ Wk_t,
    const short* __restrict__ Wv_t, short* __restrict__ K_ws,
    short* __restrict__ V_ws) {
  const int t = threadIdx.x, w = t >> 6, lane = t & 63;
  const int l15 = lane & 15, q = lane >> 4;
  const int m0 = (blockIdx.x * 4 + w) * 16;
  const int y = blockIdx.y;
  const bool isK = (y < 8);
  const int h = y & 7;
  const short* __restrict__ Wt = isK ? Wk_t : Wv_t;
  const int arow = (m0 + l15 < 616) ? (m0 + l15) : 615;

  const f32x4 z = {0.f, 0.f, 0.f, 0.f};
  f32x4 acc[4] = {z, z, z, z};
  for (int k0 = 0; k0 < 1024; k0 += 32) {
    const bf16x8 a = *(const bf16x8*)(kv_bf + arow*1024 + k0 + q*8);
    #pragma unroll
    for (int nt = 0; nt < 4; ++nt) {
      const int n = h*64 + nt*16 + l15;
      const bf16x8 bfr = *(const bf16x8*)(Wt + n*1024 + k0 + q*8);
      acc[nt] = __builtin_amdgcn_mfma_f32_16x16x32_bf16(a, bfr, acc[nt], 0, 0, 0);
    }
  }
  #pragma unroll
  for (int nt = 0; nt < 4; ++nt) {
    const int d = nt*16 + l15;
    #pragma unroll
    for (int r = 0; r < 4; ++r) {
      const int row = m0 + q*4 + r;
      if (row < 616) {
        const int b = (int)(((unsigned)row * 54472u) >> 22);   // row/77
        const int s = row - b*77;
        if (isK) K_ws[((b*8 + h)*80 + s)*64 + d] = f2bf(acc[nt][r]);
        else     V_ws[((b*8 + h)*64 + d)*96 + s] = f2bf(acc[nt][r]);
      }
    }
  }
}

// ---------------------------------------------------------------------------
// qproj: X_bf [32768][320] @ Wq_t[512][320] -> Q_ws [32768][512] bf16.
// m97-style: BM=128 tok, BN=256 j, BK=32; LDS via global_load_lds width-16.
// OPERANDS SWAPPED vs R8: A=Wq_t (j rows), B=X (token rows) so D=[j][tok]
// and the epilogue becomes packed 8B s16x4 stores (4 consecutive j per lane).
// wave = 8 j-tiles x 4 tok-tiles. grid 512 blocks = 2/CU.
// ---------------------------------------------------------------------------
__global__ __launch_bounds__(256, 2) void qproj_kernel(
    const short* __restrict__ X_bf, const short* __restrict__ Wq_t,
    short* __restrict__ Q_ws) {
  const int t = threadIdx.x, w = t >> 6, lane = t & 63;
  const int l15 = lane & 15, q = lane >> 4;
  const int m0 = (blockIdx.x >> 1) * 128;  // token base
  const int n0 = (blockIdx.x & 1) * 256;   // j base
  const int wm = w & 1, wn = w >> 1;       // wm: tok half, wn: j half

  __shared__ short tile[12288];  // X[128][32] @0, Wq[256][32] @4096 (shorts)

  const f32x4 z = {0.f, 0.f, 0.f, 0.f};
  f32x4 acc[8][4];               // [j-tile][tok-tile]
  #pragma unroll
  for (int jt = 0; jt < 8; ++jt)
    #pragma unroll
    for (int tt = 0; tt < 4; ++tt) acc[jt][tt] = z;

  for (int it = 0; it < 10; ++it) {
    const int k0 = it * 32;
    if (it) __syncthreads();
    #pragma unroll
    for (int p = 0; p < 2; ++p) {
      const int f = p*256 + t, row = f >> 2, c4 = f & 3;
      gll16(tile + f*8, X_bf + (size_t)(m0 + row)*320 + k0 + c4*8);
    }
    #pragma unroll
    for (int p = 0; p < 4; ++p) {
      const int f = p*256 + t, row = f >> 2, c4 = f & 3;
      gll16(tile + 4096 + f*8, Wq_t + (size_t)(n0 + row)*320 + k0 + c4*8);
    }
    __syncthreads();
    bf16x8 a[8], bb[4];
    #pragma unroll
    for (int jt = 0; jt < 8; ++jt)
      a[jt] = *(const bf16x8*)(tile + 4096 + (wn*128 + jt*16 + l15)*32 + q*8);
    #pragma unroll
    for (int tt = 0; tt < 4; ++tt)
      bb[tt] = *(const bf16x8*)(tile + (wm*64 + tt*16 + l15)*32 + q*8);
    #pragma unroll
    for (int jt = 0; jt < 8; ++jt)
      #pragma unroll
      for (int tt = 0; tt < 4; ++tt)
        acc[jt][tt] = __builtin_amdgcn_mfma_f32_16x16x32_bf16(a[jt], bb[tt], acc[jt][tt], 0, 0, 0);
  }
  // D=[j][tok]: col=tok=l15, rows j=q*4+r -> packed 8B stores
  #pragma unroll
  for (int tt = 0; tt < 4; ++tt) {
    short* rowp = Q_ws + (size_t)(m0 + wm*64 + tt*16 + l15)*512 + n0 + wn*128;
    #pragma unroll
    for (int jt = 0; jt < 8; ++jt) {
      s16x4 pv;
      #pragma unroll
      for (int r = 0; r < 4; ++r) pv[r] = f2bf(acc[jt][tt][r]);
      *(s16x4*)(rowp + jt*16 + q*4) = pv;
    }
  }
}

// ---------------------------------------------------------------------------
// attncore: 4 waves/block; each wave = 32 tokens (2 n-tiles) x 1 head,
// fully independent. Q pre-scaled by 0.125 (folded into Wq_t).
// ---------------------------------------------------------------------------
__global__ __launch_bounds__(256) void attncore_kernel(
    const short* __restrict__ Q_ws, const short* __restrict__ K_ws,
    const short* __restrict__ V_ws, short* __restrict__ O_ws) {
  const int t = threadIdx.x, w = t >> 6, lane = t & 63;
  const int unit = blockIdx.x * 4 + w;
  const int h = unit & 7;
  const int g = unit >> 3;                 // 32-token tile 0..1023
  const int b = g >> 7;
  const int n0 = (g & 127) * 32;
  const int l15 = lane & 15, q = lane >> 4;

  __shared__ short scr[4 * 32 * 104];      // per-wave P scratch
  short* scrw = scr + w * 32 * 104;
  for (int i = lane; i < 32*104/2; i += 64) ((unsigned*)scrw)[i] = 0u;

  const short* __restrict__ Kh = K_ws + (size_t)(b*8 + h) * 80 * 64;
  const short* __restrict__ Vh = V_ws + (size_t)(b*8 + h) * 64 * 96;
  size_t tokrow[2];
  #pragma unroll
  for (int nt = 0; nt < 2; ++nt) tokrow[nt] = (size_t)(b*NN + n0 + nt*16 + l15);

  const f32x4 z = {0.f, 0.f, 0.f, 0.f};
  f32x4 qk[2][5];
  #pragma unroll
  for (int nt = 0; nt < 2; ++nt)
    #pragma unroll
    for (int st = 0; st < 5; ++st) qk[nt][st] = z;
  #pragma unroll
  for (int f = 0; f < 2; ++f) {
    bf16x8 bq[2];
    #pragma unroll
    for (int nt = 0; nt < 2; ++nt)
      bq[nt] = *(const bf16x8*)(Q_ws + tokrow[nt]*512 + h*64 + f*32 + q*8);
    #pragma unroll
    for (int st = 0; st < 5; ++st) {
      const bf16x8 a = *(const bf16x8*)(Kh + (st*16 + l15)*64 + f*32 + q*8);
      #pragma unroll
      for (int nt = 0; nt < 2; ++nt)
        qk[nt][st] = __builtin_amdgcn_mfma_f32_16x16x32_bf16(a, bq[nt], qk[nt][st], 0, 0, 0);
    }
  }

  #pragma unroll
  for (int nt = 0; nt < 2; ++nt) {
    float mx = -1e30f;
    #pragma unroll
    for (int st = 0; st < 5; ++st)
      #pragma unroll
      for (int r = 0; r < 4; ++r) {
        const int s = st*16 + q*4 + r;
        const float vv = (s < SKV) ? qk[nt][st][r] : -1e30f;
        qk[nt][st][r] = vv;
        mx = fmaxf(mx, vv);
      }
    mx = fmaxf(mx, __shfl_xor(mx, 16));
    mx = fmaxf(mx, __shfl_xor(mx, 32));
    float sum = 0.f;
    #pragma unroll
    for (int st = 0; st < 5; ++st)
      #pragma unroll
      for (int r = 0; r < 4; ++r) {
        const int s = st*16 + q*4 + r;
        const float e = (s < SKV) ? __expf(qk[nt][st][r] - mx) : 0.f;
        qk[nt][st][r] = e;
        sum += e;
      }
    sum += __shfl_xor(sum, 16);
    sum += __shfl_xor(sum, 32);
    const float inv = 1.0f / sum;
    #pragma unroll
    for (int st = 0; st < 5; ++st) {
      s16x4 pv;
      #pragma unroll
      for (int r = 0; r < 4; ++r) pv[r] = f2bf(qk[nt][st][r] * inv);
      *(s16x4*)(scrw + (nt*16 + l15)*104 + st*16 + q*4) = pv;
    }
  }

  f32x4 ov[2][4];
  #pragma unroll
  for (int nt = 0; nt < 2; ++nt)
    #pragma unroll
    for (int dt = 0; dt < 4; ++dt) ov[nt][dt] = z;
  #pragma unroll
  for (int f = 0; f < 3; ++f) {
    bf16x8 bp[2];
    #pragma unroll
    for (int nt = 0; nt < 2; ++nt)
      bp[nt] = *(const bf16x8*)(scrw + (nt*16 + l15)*104 + f*32 + q*8);
    #pragma unroll
    for (int dt = 0; dt < 4; ++dt) {
      const bf16x8 a = *(const bf16x8*)(Vh + (dt*16 + l15)*96 + f*32 + q*8);
      #pragma unroll
      for (int nt = 0; nt < 2; ++nt)
        ov[nt][dt] = __builtin_amdgcn_mfma_f32_16x16x32_bf16(a, bp[nt], ov[nt][dt], 0, 0, 0);
    }
  }
  #pragma unroll
  for (int nt = 0; nt < 2; ++nt)
    #pragma unroll
    for (int dt = 0; dt < 4; ++dt) {
      s16x4 pv;
      #pragma unroll
      for (int r = 0; r < 4; ++r) pv[r] = f2bf(ov[nt][dt][r]);
      *(s16x4*)(O_ws + tokrow[nt]*512 + h*64 + dt*16 + q*4) = pv;
    }
}

// ---------------------------------------------------------------------------
// outproj: out^T = Wo_t[320][512] @ O_ws^T -> out[b][c][n] + bias.
// Full-C tile: BM=320, BN=64 tok, BK=32; every O_ws row fetched once.
// LDS 24 KB; grid 512 = 2/CU; wave = 5 m-tiles (80 c) x 4 n-tiles.
// ---------------------------------------------------------------------------
__global__ __launch_bounds__(256) void outproj_kernel(
    const short* __restrict__ O_ws, const short* __restrict__ Wo_t,
    const float* __restrict__ bo, float* __restrict__ out) {
  const int t = threadIdx.x, w = t >> 6, lane = t & 63;
  const int l15 = lane & 15, q = lane >> 4;
  const int t0 = blockIdx.x * 64;          // token base

  __shared__ short tile[12288];  // A=Wo_t[320][32] @0, B=O[64][32] @10240

  const f32x4 z = {0.f, 0.f, 0.f, 0.f};
  f32x4 acc[5][4];
  #pragma unroll
  for (int mt = 0; mt < 5; ++mt)
    #pragma unroll
    for (int nt = 0; nt < 4; ++nt) acc[mt][nt] = z;

  for (int it = 0; it < 16; ++it) {
    const int k0 = it * 32;
    if (it) __syncthreads();
    #pragma unroll
    for (int p = 0; p < 5; ++p) {
      const int f = p*256 + t, row = f >> 2, c4 = f & 3;
      gll16(tile + f*8, Wo_t + (size_t)row*512 + k0 + c4*8);
    }
    {
      const int row = t >> 2, c4 = t & 3;
      gll16(tile + 10240 + t*8, O_ws + (size_t)(t0 + row)*512 + k0 + c4*8);
    }
    __syncthreads();
    bf16x8 a[5], bb[4];
    #pragma unroll
    for (int mt = 0; mt < 5; ++mt)
      a[mt] = *(const bf16x8*)(tile + (w*80 + mt*16 + l15)*32 + q*8);
    #pragma unroll
    for (int nt = 0; nt < 4; ++nt)
      bb[nt] = *(const bf16x8*)(tile + 10240 + (nt*16 + l15)*32 + q*8);
    #pragma unroll
    for (int mt = 0; mt < 5; ++mt)
      #pragma unroll
      for (int nt = 0; nt < 4; ++nt)
        acc[mt][nt] = __builtin_amdgcn_mfma_f32_16x16x32_bf16(a[mt], bb[nt], acc[mt][nt], 0, 0, 0);
  }
  const int b = t0 >> 12, n = t0 & 4095;
  #pragma unroll
  for (int mt = 0; mt < 5; ++mt)
    #pragma unroll
    for (int r = 0; r < 4; ++r) {
      const int c = w*80 + mt*16 + q*4 + r;
      const float bv = bo[c];
      float* rowp = out + ((size_t)(b*CC + c))*NN + n;
      #pragma unroll
      for (int nt = 0; nt < 4; ++nt)
        rowp[nt*16 + l15] = acc[mt][nt][r] + bv;
    }
}

// ---------------------------------------------------------------------------
extern "C" void kernel_launch(void* const* d_in, const int* in_sizes, int n_in,
                              void* d_out, int out_size, void* d_ws, size_t ws_size,
                              hipStream_t stream) {
  const float* query = (const float*)d_in[0];
  const float* kv    = (const float*)d_in[1];
  const float* Wq    = (const float*)d_in[2];
  const float* Wk    = (const float*)d_in[3];
  const float* Wv    = (const float*)d_in[4];
  const float* Wo    = (const float*)d_in[5];
  const float* bo    = (const float*)d_in[6];
  float* out = (float*)d_out;

  char* p = (char*)d_ws;
  // persistent region
  short* K_ws  = (short*)(p);             //   819,200 B [8][8][80][64]
  short* V_ws  = (short*)(p +   819200);  //   983,040 B [8][8][64][96]
  short* Wq_t  = (short*)(p +  1802240);  //   327,680 B [512][320] (x SCALE)
  short* Wo_t  = (short*)(p +  2129920);  //   327,680 B [320][512]
  short* Q_ws  = (short*)(p +  2457600);  // 33,554,432 B [32768][512]
  // region B: X_bf/kv_bf/Wk_t/Wv_t (dead after qproj) overlaid by O_ws
  char* pb = p + 36012032;
  short* X_bf  = (short*)(pb);            // 20,971,520 B [32768][320]
  short* kv_bf = (short*)(pb + 20971520); //  1,261,568 B [616][1024]
  short* Wk_t  = (short*)(pb + 22233088); //  1,048,576 B [512][1024]
  short* Wv_t  = (short*)(pb + 23281664); //  1,048,576 B [512][1024]
  short* O_ws  = (short*)(pb);            // 33,554,432 B [32768][512] (overlay)

  prep_kernel<<<3952, 256, 0, stream>>>(kv, Wk, Wv, Wq, Wo, query, kv_bf,
                                        Wk_t, Wv_t, Wq_t, Wo_t, X_bf,
                                        (unsigned*)p);
  kvproj_kernel<<<dim3(10, 16), 256, 0, stream>>>(kv_bf, Wk_t, Wv_t, K_ws, V_ws);
  qproj_kernel<<<512, 256, 0, stream>>>(X_bf, Wq_t, Q_ws);
  attncore_kernel<<<2048, 256, 0, stream>>>(Q_ws, K_ws, V_ws, O_ws);
  outproj_kernel<<<512, 256, 0, stream>>>(O_ws, Wo_t, bo, out);
}